// Round 8
// baseline (108.961 us; speedup 1.0000x reference)
//
#include <hip/hip_runtime.h>
#include <hip/hip_bf16.h>

// B=8, T=4096, C=1024, HS=64. Single attention head, causal, scale = C^-0.5.
// Pipeline: wprep (W -> Wt bf16 [192][1024]) ; proj (q,k bf16 [b][t][64], vT bf16 [b][64][t]) ;
//           flash (split-KV causal online-softmax, swapped-operand MFMA, 128-row q-tiles) ;
//           combine (merge the two KV halves, normalize, fp32 out).
// Q is pre-scaled by log2(e)/32 in proj, so QK^T is directly log2-domain.

typedef __attribute__((ext_vector_type(8))) short short8;
typedef __attribute__((ext_vector_type(4))) float f32x4;

#define NB 8
#define NT 4096
#define NC 1024
#define NH 64

__device__ __forceinline__ unsigned short f2bf(float f) {
    unsigned int u = __builtin_bit_cast(unsigned int, f);
    u += 0x7fffu + ((u >> 16) & 1u);   // RNE
    return (unsigned short)(u >> 16);
}

__device__ __forceinline__ unsigned cvt_pk_bf16(float lo, float hi) {
    unsigned r;
    asm("v_cvt_pk_bf16_f32 %0, %1, %2" : "=v"(r) : "v"(lo), "v"(hi));
    return r;
}

// async global->LDS, 16B per lane; LDS dest = wave-uniform base + lane*16
#define GLOAD16(gp, lp)                                                        \
    __builtin_amdgcn_global_load_lds(                                          \
        (const __attribute__((address_space(1))) void*)(gp),                   \
        (__attribute__((address_space(3))) void*)(lp), 16, 0, 0)

// ---------------- W prep: Wt[n][c] = W_{n/64}[c][n%64] as bf16 -----------------
__global__ __launch_bounds__(256) void wprep_kernel(
    const float* __restrict__ Wk, const float* __restrict__ Wq,
    const float* __restrict__ Wv, unsigned short* __restrict__ Wt)
{
    int n = blockIdx.x;            // 0..191
    int which = n >> 6, h = n & 63;
    const float* W = (which == 0) ? Wk : (which == 1) ? Wq : Wv;
    for (int c = threadIdx.x; c < NC; c += 256)
        Wt[(size_t)n * NC + c] = f2bf(W[(size_t)c * NH + h]);
}

// ---------------- Projection GEMM: [32768 x 1024] @ [1024 x 192] ---------------
// m97-style 2-phase: double-buffered LDS, global_load_lds staging (width 16),
// BK=64. A tile [64 rows][64 k] fp32 (16 KB), B tile [192 n][64 k] bf16 (24 KB).
__global__ __launch_bounds__(256, 2) void proj_kernel(
    const float* __restrict__ x, const unsigned short* __restrict__ Wt,
    unsigned short* __restrict__ qws, unsigned short* __restrict__ kws,
    unsigned short* __restrict__ vtws)
{
    __shared__ float          Albuf[2][64 * 64];           // 2 x 16 KB
    __shared__ unsigned short Blbuf[2][192 * 64];          // 2 x 24 KB

    const int lane = threadIdx.x & 63;
    const int wave = threadIdx.x >> 6;
    const int l15 = lane & 15;
    const int kg = lane >> 4;                  // 0..3
    const int m0 = blockIdx.x * 64;

    const float* aSrc[4];
#pragma unroll
    for (int i = 0; i < 4; ++i) {
        int rlo = lane >> 4;
        int r = 4 * (wave * 4 + i) + rlo;
        int g = (lane & 15) ^ (4 * i + rlo);
        aSrc[i] = x + (size_t)(m0 + r) * NC + g * 4;
    }
    const unsigned short* bSrc[6];
#pragma unroll
    for (int i = 0; i < 6; ++i) {
        int r = 8 * (wave * 6 + i) + (lane >> 3);
        int g = (lane & 7) ^ (lane >> 3);
        bSrc[i] = Wt + (size_t)r * NC + g * 8;
    }

    f32x4 acc[12];
#pragma unroll
    for (int i = 0; i < 12; ++i) acc[i] = f32x4{0.f, 0.f, 0.f, 0.f};

#pragma unroll
    for (int i = 0; i < 4; ++i)
        GLOAD16(aSrc[i], (char*)&Albuf[0][0] + (wave * 4 + i) * 1024);
#pragma unroll
    for (int i = 0; i < 6; ++i)
        GLOAD16(bSrc[i], (char*)&Blbuf[0][0] + (wave * 6 + i) * 1024);
    __syncthreads();

    int buf = 0;
    for (int kc = 0; kc < 16; ++kc) {
        if (kc < 15) {
#pragma unroll
            for (int i = 0; i < 4; ++i)
                GLOAD16(aSrc[i] + (kc + 1) * 64,
                        (char*)&Albuf[buf ^ 1][0] + (wave * 4 + i) * 1024);
#pragma unroll
            for (int i = 0; i < 6; ++i)
                GLOAD16(bSrc[i] + (kc + 1) * 64,
                        (char*)&Blbuf[buf ^ 1][0] + (wave * 6 + i) * 1024);
        }

        const char* Ab = (const char*)&Albuf[buf][0];
        const char* Bb = (const char*)&Blbuf[buf][0];
#pragma unroll
        for (int sub = 0; sub < 2; ++sub) {
            const int r = wave * 16 + l15;
            const int g0 = sub * 8 + kg * 2;
            f32x4 a0 = *(const f32x4*)(Ab + r * 256 + ((g0 ^ l15) * 16));
            f32x4 a1 = *(const f32x4*)(Ab + r * 256 + (((g0 + 1) ^ l15) * 16));
            short8 a;
            a[0] = (short)f2bf(a0[0]); a[1] = (short)f2bf(a0[1]);
            a[2] = (short)f2bf(a0[2]); a[3] = (short)f2bf(a0[3]);
            a[4] = (short)f2bf(a1[0]); a[5] = (short)f2bf(a1[1]);
            a[6] = (short)f2bf(a1[2]); a[7] = (short)f2bf(a1[3]);
#pragma unroll
            for (int nt = 0; nt < 12; ++nt) {
                int rb = nt * 16 + l15;
                short8 bfrag = *(const short8*)(
                    Bb + rb * 128 + ((((sub << 2) + kg) ^ (l15 & 7)) * 16));
                acc[nt] = __builtin_amdgcn_mfma_f32_16x16x32_bf16(a, bfrag, acc[nt], 0, 0, 0);
            }
        }
        __syncthreads();
        buf ^= 1;
    }

    const float cs = 0.04508422f;   // log2(e) / 32  (folded into q)
    const int crow0 = m0 + wave * 16 + (kg << 2);
#pragma unroll
    for (int nt = 0; nt < 12; ++nt) {
        int n = nt * 16 + l15;
        int which = n >> 6;
        int h = n & 63;
#pragma unroll
        for (int r = 0; r < 4; ++r) {
            int gm = crow0 + r;
            float av = acc[nt][r];
            if (which == 1) av *= cs;
            unsigned short v = f2bf(av);
            if (which == 0) {
                kws[(size_t)gm * NH + h] = v;
            } else if (which == 1) {
                qws[(size_t)gm * NH + h] = v;
            } else {
                int bb = gm >> 12, tt = gm & 4095;
                vtws[((size_t)(bb * NH + h)) * NT + tt] = v;
            }
        }
    }
}

// ---------------- Flash attention (causal, swapped operands, split-KV) ---------
// 512 blocks = 2 KV-halves x (8 batches x 32 q-tiles of 128 rows).
// 4 waves x 32 q-rows (two 16-row MFMA sets share every K/V fragment read).
// Causal tiles [0..2qt+1] split into two equal halves (qt+1 each); blocks
// i and i+256 pair qt with 31-qt -> constant per-CU work.
// Shared running max m_r per lane covers both q-sets (any m >= row max is
// valid; degenerate all-masked rows give m=-1e30 which combine zeroes out).
__global__ __launch_bounds__(256) void flash_kernel(
    const unsigned short* __restrict__ qws, const unsigned short* __restrict__ kws,
    const unsigned short* __restrict__ vtws,
    float* __restrict__ opart, float* __restrict__ mlpart)
{
    __shared__ unsigned short Kbuf[2][64 * 64];    // 2 x 8 KB
    __shared__ unsigned short Vbuf[2][64 * 64];    // 2 x 8 KB
    __shared__ unsigned short Plds[4 * 32 * 64];   // per-wave 32x64 P strips (16 KB)

    const int id = blockIdx.x;
    const int kvh = id >> 8;           // 0: tiles [0,qt+1), 1: tiles [qt+1,2qt+2)
    const int b = id & 7;
    const int j5 = (id & 255) >> 3;    // 0..31
    const int qt = kvh ? j5 : (31 - j5);   // heavy-first in each half-set
    const int k0 = kvh ? (qt + 1) : 0;
    const int k1 = kvh ? (2 * qt + 2) : (qt + 1);
    const int pid = (kvh << 8) | (b << 5) | qt;

    float* mlp = mlpart + (size_t)pid * 256;
    float* op  = opart + (size_t)pid * 8192;

    const int lane = threadIdx.x & 63;
    const int wave = threadIdx.x >> 6;
    const int l15 = lane & 15;
    const int kg = lane >> 4;

    // ---- staging sources (pre-inverse-swizzled, loop-invariant per lane) ----
    const int sg = (lane & 7) ^ (lane >> 3);   // swizzled source granule
    const unsigned short* kSrc[2];
    const unsigned short* vSrc[2];
#pragma unroll
    for (int j = 0; j < 2; ++j) {
        int r = 16 * wave + 8 * j + (lane >> 3);   // tile-local row 0..63
        kSrc[j] = kws + ((size_t)(b * NT) + r) * NH + sg * 8;
        vSrc[j] = vtws + ((size_t)(b * NH + r)) * NT + sg * 8;
    }

    // Q fragments (pre-scaled): qf[qs][ks], q-row = qt*128 + wave*32 + qs*16 + l15
    short8 qf[2][2];
#pragma unroll
    for (int qs = 0; qs < 2; ++qs) {
        const unsigned short* qp =
            qws + ((size_t)(b * NT + qt * 128 + wave * 32 + qs * 16 + l15)) * NH + kg * 8;
        qf[qs][0] = *(const short8*)(qp);
        qf[qs][1] = *(const short8*)(qp + 32);
    }

    f32x4 o0[4], o1[4];    // O^T per q-set: o[dt][r] = O[q][d = dt*16 + kg*4 + r]
#pragma unroll
    for (int dt = 0; dt < 4; ++dt) {
        o0[dt] = f32x4{0.f, 0.f, 0.f, 0.f};
        o1[dt] = f32x4{0.f, 0.f, 0.f, 0.f};
    }
    float m_r = -INFINITY;        // shared across both q-sets (per-lane)
    float l0_r = 0.f, l1_r = 0.f; // per-lane partial sums (own 16 keys, per q-set)

    char* pw = (char*)Plds + wave * 4096;
    const int pswz = (l15 & 7) << 4;
    const int qb0 = qt * 128 + wave * 32;   // block-local q base, q-set 0
    const int qb1 = qb0 + 16;

    // prologue: stage tile k0 into buf 0
#pragma unroll
    for (int j = 0; j < 2; ++j) {
        int i = 2 * wave + j;
        GLOAD16(kSrc[j] + (size_t)k0 * 64 * NH, (char*)Kbuf[0] + i * 1024);
        GLOAD16(vSrc[j] + (size_t)k0 * 64,      (char*)Vbuf[0] + i * 1024);
    }
    __syncthreads();

    int cur = 0;
    for (int kv = k0; kv < k1; ++kv) {
        // stage next tile into the other buffer (async, fire-and-forget)
        if (kv + 1 < k1) {
#pragma unroll
            for (int j = 0; j < 2; ++j) {
                int i = 2 * wave + j;
                GLOAD16(kSrc[j] + (size_t)(kv + 1) * 64 * NH,
                        (char*)Kbuf[cur ^ 1] + i * 1024);
                GLOAD16(vSrc[j] + (size_t)(kv + 1) * 64,
                        (char*)Vbuf[cur ^ 1] + i * 1024);
            }
        }

        const char* Kb = (const char*)Kbuf[cur];
        const char* Vb = (const char*)Vbuf[cur];

        // S^T = mfma(K, Q): each K-fragment feeds BOTH q-sets
        f32x4 st0[4], st1[4];
#pragma unroll
        for (int jt = 0; jt < 4; ++jt) {
            st0[jt] = f32x4{0.f, 0.f, 0.f, 0.f};
            st1[jt] = f32x4{0.f, 0.f, 0.f, 0.f};
        }
#pragma unroll
        for (int ks = 0; ks < 2; ++ks) {
            const int cbb = ks * 64 + kg * 16;
#pragma unroll
            for (int jt = 0; jt < 4; ++jt) {
                int krow = jt * 16 + l15;
                short8 kf = *(const short8*)(Kb + krow * 128 +
                                             (cbb ^ ((krow & 7) << 4)));
                st0[jt] = __builtin_amdgcn_mfma_f32_16x16x32_bf16(kf, qf[0][ks], st0[jt], 0, 0, 0);
                st1[jt] = __builtin_amdgcn_mfma_f32_16x16x32_bf16(kf, qf[1][ks], st1[jt], 0, 0, 0);
            }
        }

        // causal mask (elementwise only when tile can exceed the q-set's rows)
        const int kb = kv << 6;
        if (kb + 63 > qb0) {
#pragma unroll
            for (int jt = 0; jt < 4; ++jt)
#pragma unroll
                for (int r = 0; r < 4; ++r)
                    if (kb + jt * 16 + (kg << 2) + r > qb0 + l15)
                        st0[jt][r] = -1e30f;
        }
        if (kb + 63 > qb1) {
#pragma unroll
            for (int jt = 0; jt < 4; ++jt)
#pragma unroll
                for (int r = 0; r < 4; ++r)
                    if (kb + jt * 16 + (kg << 2) + r > qb1 + l15)
                        st1[jt][r] = -1e30f;
        }

        // lane-local max over own 16 keys, both q-sets (no cross-lane)
        float lmax;
        {
            float a0 = fmaxf(fmaxf(st0[0][0], st0[0][1]), fmaxf(st0[0][2], st0[0][3]));
            float a1 = fmaxf(fmaxf(st0[1][0], st0[1][1]), fmaxf(st0[1][2], st0[1][3]));
            float a2 = fmaxf(fmaxf(st0[2][0], st0[2][1]), fmaxf(st0[2][2], st0[2][3]));
            float a3 = fmaxf(fmaxf(st0[3][0], st0[3][1]), fmaxf(st0[3][2], st0[3][3]));
            float b0 = fmaxf(fmaxf(st1[0][0], st1[0][1]), fmaxf(st1[0][2], st1[0][3]));
            float b1 = fmaxf(fmaxf(st1[1][0], st1[1][1]), fmaxf(st1[1][2], st1[1][3]));
            float b2 = fmaxf(fmaxf(st1[2][0], st1[2][1]), fmaxf(st1[2][2], st1[2][3]));
            float b3 = fmaxf(fmaxf(st1[3][0], st1[3][1]), fmaxf(st1[3][2], st1[3][3]));
            lmax = fmaxf(fmaxf(fmaxf(a0, a1), fmaxf(a2, a3)),
                         fmaxf(fmaxf(b0, b1), fmaxf(b2, b3)));
        }

        // defer-max: rescale only when some row grew past m+8 (rare)
        if (!__all(lmax <= m_r + 8.0f)) {
            float pmax = lmax;
            pmax = fmaxf(pmax, __shfl_xor(pmax, 16));
            pmax = fmaxf(pmax, __shfl_xor(pmax, 32));
            float mn = fmaxf(m_r, pmax);
            float alpha = __builtin_amdgcn_exp2f(m_r - mn);
            m_r = mn;
            l0_r *= alpha; l1_r *= alpha;
#pragma unroll
            for (int dt = 0; dt < 4; ++dt)
#pragma unroll
                for (int r = 0; r < 4; ++r) {
                    o0[dt][r] *= alpha;
                    o1[dt][r] *= alpha;
                }
        }

        // P = exp2(S - m); accumulate per-lane partial l per q-set
#pragma unroll
        for (int jt = 0; jt < 4; ++jt)
#pragma unroll
            for (int r = 0; r < 4; ++r) {
                st0[jt][r] = __builtin_amdgcn_exp2f(st0[jt][r] - m_r);
                st1[jt][r] = __builtin_amdgcn_exp2f(st1[jt][r] - m_r);
            }
        {
            float a0 = (st0[0][0] + st0[0][1]) + (st0[0][2] + st0[0][3]);
            float a1 = (st0[1][0] + st0[1][1]) + (st0[1][2] + st0[1][3]);
            float a2 = (st0[2][0] + st0[2][1]) + (st0[2][2] + st0[2][3]);
            float a3 = (st0[3][0] + st0[3][1]) + (st0[3][2] + st0[3][3]);
            l0_r += (a0 + a1) + (a2 + a3);
            float b0 = (st1[0][0] + st1[0][1]) + (st1[0][2] + st1[0][3]);
            float b1 = (st1[1][0] + st1[1][1]) + (st1[1][2] + st1[1][3]);
            float b2 = (st1[2][0] + st1[2][1]) + (st1[2][2] + st1[2][3]);
            float b3 = (st1[3][0] + st1[3][1]) + (st1[3][2] + st1[3][3]);
            l1_r += (b0 + b1) + (b2 + b3);
        }

        // pack P to bf16, per-wave LDS strip round-trip -> B-frag layout
#pragma unroll
        for (int jt = 0; jt < 4; ++jt) {
            uint2 t0, t1;
            t0.x = cvt_pk_bf16(st0[jt][0], st0[jt][1]);
            t0.y = cvt_pk_bf16(st0[jt][2], st0[jt][3]);
            t1.x = cvt_pk_bf16(st1[jt][0], st1[jt][1]);
            t1.y = cvt_pk_bf16(st1[jt][2], st1[jt][3]);
            *(uint2*)(pw + l15 * 128 + ((jt * 32 + kg * 8) ^ pswz)) = t0;
            *(uint2*)(pw + (16 + l15) * 128 + ((jt * 32 + kg * 8) ^ pswz)) = t1;
        }
        short8 pf0[2], pf1[2];
#pragma unroll
        for (int ks = 0; ks < 2; ++ks) {
            pf0[ks] = *(const short8*)(pw + l15 * 128 + ((ks * 64 + kg * 16) ^ pswz));
            pf1[ks] = *(const short8*)(pw + (16 + l15) * 128 + ((ks * 64 + kg * 16) ^ pswz));
        }

        // O^T += mfma(V^T, P^T): each V-fragment feeds BOTH q-sets
#pragma unroll
        for (int ks = 0; ks < 2; ++ks) {
            const int cbb = ks * 64 + kg * 16;
#pragma unroll
            for (int dt = 0; dt < 4; ++dt) {
                int vrow = dt * 16 + l15;
                short8 vf = *(const short8*)(Vb + vrow * 128 +
                                             (cbb ^ ((vrow & 7) << 4)));
                o0[dt] = __builtin_amdgcn_mfma_f32_16x16x32_bf16(vf, pf0[ks], o0[dt], 0, 0, 0);
                o1[dt] = __builtin_amdgcn_mfma_f32_16x16x32_bf16(vf, pf1[ks], o1[dt], 0, 0, 0);
            }
        }

        // single barrier: drains staging vmcnt + this iter's LDS reads
        __syncthreads();
        cur ^= 1;
    }

    // epilogue: reduce partial l over kg; store raw O^T + (m,l) per q-set
    float ls0 = l0_r, ls1 = l1_r;
    ls0 += __shfl_xor(ls0, 16); ls0 += __shfl_xor(ls0, 32);
    ls1 += __shfl_xor(ls1, 16); ls1 += __shfl_xor(ls1, 32);
    const int row0 = wave * 32 + l15;
    const int row1 = row0 + 16;
    float* orow0 = op + row0 * 64 + (kg << 2);
    float* orow1 = op + row1 * 64 + (kg << 2);
#pragma unroll
    for (int dt = 0; dt < 4; ++dt) {
        *(f32x4*)(orow0 + dt * 16) = o0[dt];
        *(f32x4*)(orow1 + dt * 16) = o1[dt];
    }
    if (kg == 0) {
        mlp[row0] = m_r;  mlp[128 + row0] = ls0;
        mlp[row1] = m_r;  mlp[128 + row1] = ls1;
    }
}

// ---------------- Combine: merge the two KV halves, normalize -----------------
// 256 blocks = (b, qt128). O = (eA*OA + eB*OB) / (eA*lA + eB*lB).
__global__ __launch_bounds__(256) void combine_kernel(
    const float* __restrict__ opart, const float* __restrict__ mlpart,
    float* __restrict__ out)
{
    const int cid = blockIdx.x;          // = (b<<5)|qt
    const int b = cid >> 5, qt = cid & 31;
    const float* mlA = mlpart + (size_t)cid * 256;
    const float* mlB = mlpart + (size_t)(256 + cid) * 256;
    const f32x4* oA = (const f32x4*)(opart + (size_t)cid * 8192);
    const f32x4* oB = (const f32x4*)(opart + (size_t)(256 + cid) * 8192);
    f32x4* og = (f32x4*)out;

#pragma unroll
    for (int i = 0; i < 8; ++i) {
        int g = threadIdx.x + i * 256;   // 0..2047 f32x4 groups
        int row = g >> 4;
        float mA = mlA[row], lA = mlA[128 + row];
        float mB = mlB[row], lB = mlB[128 + row];
        float ms = fmaxf(mA, mB);
        float eA = __builtin_amdgcn_exp2f(mA - ms);
        float eB = __builtin_amdgcn_exp2f(mB - ms);
        float dinv = __builtin_amdgcn_rcpf(eA * lA + eB * lB);
        f32x4 a = oA[g], c = oB[g];
        f32x4 r;
        r[0] = (eA * a[0] + eB * c[0]) * dinv;
        r[1] = (eA * a[1] + eB * c[1]) * dinv;
        r[2] = (eA * a[2] + eB * c[2]) * dinv;
        r[3] = (eA * a[3] + eB * c[3]) * dinv;
        og[((size_t)(b * NT) + qt * 128 + row) * 16 + (g & 15)] = r;
    }
}

extern "C" void kernel_launch(void* const* d_in, const int* in_sizes, int n_in,
                              void* d_out, int out_size, void* d_ws, size_t ws_size,
                              hipStream_t stream) {
    const float* x  = (const float*)d_in[0];
    const float* Wk = (const float*)d_in[1];
    const float* Wq = (const float*)d_in[2];
    const float* Wv = (const float*)d_in[3];
    float* out = (float*)d_out;

    unsigned short* ws   = (unsigned short*)d_ws;
    const size_t qkv_elems = (size_t)NB * NT * NH;   // 2M elements each
    unsigned short* qws  = ws;
    unsigned short* kws  = qws + qkv_elems;
    unsigned short* vtws = kws + qkv_elems;
    unsigned short* Wt   = vtws + qkv_elems;          // 192*1024 bf16
    float* opart  = (float*)(Wt + (size_t)192 * NC);  // 512 tiles x 8192 f32
    float* mlpart = opart + (size_t)512 * 8192;       // 512 x 256 f32

    wprep_kernel<<<dim3(192), dim3(256), 0, stream>>>(Wk, Wq, Wv, Wt);
    proj_kernel<<<dim3(512), dim3(256), 0, stream>>>(x, Wt, qws, kws, vtws);
    flash_kernel<<<dim3(512), dim3(256), 0, stream>>>(qws, kws, vtws, opart, mlpart);
    combine_kernel<<<dim3(256), dim3(256), 0, stream>>>(opart, mlpart, out);
}

// Round 9
// 86.965 us; speedup vs baseline: 1.2529x; 1.2529x over previous
//
#include <hip/hip_runtime.h>
#include <hip/hip_bf16.h>

// B=8, T=4096, C=1024, HS=64. Single attention head, causal, scale = C^-0.5.
// Pipeline: wprep (W -> Wt bf16 [192][1024]) ; proj (q,k bf16, vT bf16; counted-vmcnt pipeline) ;
//           flash (split-KV causal online-softmax, swapped-operand MFMA, gload_lds staging) ;
//           combine (merge the two KV halves, normalize, fp32 out).
// Q is pre-scaled by log2(e)/32 in proj, so QK^T is directly log2-domain.

typedef __attribute__((ext_vector_type(8))) short short8;
typedef __attribute__((ext_vector_type(4))) float f32x4;

#define NB 8
#define NT 4096
#define NC 1024
#define NH 64

__device__ __forceinline__ unsigned short f2bf(float f) {
    unsigned int u = __builtin_bit_cast(unsigned int, f);
    u += 0x7fffu + ((u >> 16) & 1u);   // RNE
    return (unsigned short)(u >> 16);
}

__device__ __forceinline__ unsigned cvt_pk_bf16(float lo, float hi) {
    unsigned r;
    asm("v_cvt_pk_bf16_f32 %0, %1, %2" : "=v"(r) : "v"(lo), "v"(hi));
    return r;
}

// async global->LDS, 16B per lane; LDS dest = wave-uniform base + lane*16
#define GLOAD16(gp, lp)                                                        \
    __builtin_amdgcn_global_load_lds(                                          \
        (const __attribute__((address_space(1))) void*)(gp),                   \
        (__attribute__((address_space(3))) void*)(lp), 16, 0, 0)

// ---------------- W prep: Wt[n][c] = W_{n/64}[c][n%64] as bf16 -----------------
__global__ __launch_bounds__(256) void wprep_kernel(
    const float* __restrict__ Wk, const float* __restrict__ Wq,
    const float* __restrict__ Wv, unsigned short* __restrict__ Wt)
{
    int n = blockIdx.x;            // 0..191
    int which = n >> 6, h = n & 63;
    const float* W = (which == 0) ? Wk : (which == 1) ? Wq : Wv;
    for (int c = threadIdx.x; c < NC; c += 256)
        Wt[(size_t)n * NC + c] = f2bf(W[(size_t)c * NH + h]);
}

// ---------------- Projection GEMM: [32768 x 1024] @ [1024 x 192] ---------------
// Counted-vmcnt pipeline (T4-lite): BK=32, 4 LDS buffers (20 KB each, 80 KB),
// depth-2 prefetch. Per iter: issue stage(k+2) -> s_waitcnt vmcnt(10) (chunk k
// landed; k+1/k+2 stay in flight) -> raw s_barrier -> compute(k).
// Buffer safety: stage(k+2) writes buf[(k+2)&3], last read by compute(k-2),
// which all waves finished before barrier(k-1); issue is after barrier(k-1).
// Per chunk: A tile [64 r][32 k] fp32 (8 KB, 2 instr/wave), B tile [192 n][32 k]
// bf16 (12 KB, 3 instr/wave). Swizzle per rule #21: linear LDS dest,
// inverse-XOR global src, XOR on ds_read (A: g^(r&7) of 8; B: g^(r&3) of 4).
__global__ __launch_bounds__(256, 2) void proj_kernel(
    const float* __restrict__ x, const unsigned short* __restrict__ Wt,
    unsigned short* __restrict__ qws, unsigned short* __restrict__ kws,
    unsigned short* __restrict__ vtws)
{
    __shared__ char lds[4][20480];   // [buf]: A at 0 (8 KB), B at 8192 (12 KB)

    const int lane = threadIdx.x & 63;
    const int wave = threadIdx.x >> 6;
    const int l15 = lane & 15;
    const int kg = lane >> 4;                  // 0..3
    const int m0 = blockIdx.x * 64;

    // ---- staging source pointers (pre-inverse-swizzled per lane) ----
    // A: 8 instrs (2/wave); instr i covers rows 8i..8i+7; lane -> row 8i+(l>>3),
    //    phys granule l&7; source granule (l&7)^(l>>3) (8i = 0 mod 8).
    const int agS = (lane & 7) ^ (lane >> 3);
    const float* aSrc[2];
#pragma unroll
    for (int j = 0; j < 2; ++j) {
        int i = wave * 2 + j;
        int r = 8 * i + (lane >> 3);
        aSrc[j] = x + (size_t)(m0 + r) * NC + agS * 4;
    }
    // B: 12 instrs (3/wave); instr u covers rows 16u..16u+15; lane -> row
    //    16u+(l>>2), phys granule l&3; source granule (l&3)^((l>>2)&3).
    const int bgS = (lane & 3) ^ ((lane >> 2) & 3);
    const unsigned short* bSrc[3];
#pragma unroll
    for (int j = 0; j < 3; ++j) {
        int u = wave * 3 + j;
        int r = 16 * u + (lane >> 2);
        bSrc[j] = Wt + (size_t)r * NC + bgS * 8;
    }

    f32x4 acc[12];
#pragma unroll
    for (int i = 0; i < 12; ++i) acc[i] = f32x4{0.f, 0.f, 0.f, 0.f};

    // stage chunk c into buf[c&3] (5 instrs per wave)
#define STAGE_CHUNK(c)                                                         \
    do {                                                                       \
        char* base_ = lds[(c) & 3];                                            \
        _Pragma("unroll")                                                      \
        for (int j = 0; j < 2; ++j)                                            \
            GLOAD16(aSrc[j] + (c) * 32, base_ + (wave * 2 + j) * 1024);        \
        _Pragma("unroll")                                                      \
        for (int j = 0; j < 3; ++j)                                            \
            GLOAD16(bSrc[j] + (c) * 32, base_ + 8192 + (wave * 3 + j) * 1024); \
    } while (0)

    STAGE_CHUNK(0);
    STAGE_CHUNK(1);

    for (int kc = 0; kc < 32; ++kc) {
        if (kc < 30) {
            STAGE_CHUNK(kc + 2);
            asm volatile("s_waitcnt vmcnt(10)" ::: "memory");
        } else if (kc == 30) {
            asm volatile("s_waitcnt vmcnt(5)" ::: "memory");
        } else {
            asm volatile("s_waitcnt vmcnt(0)" ::: "memory");
        }
        __builtin_amdgcn_sched_barrier(0);
        __builtin_amdgcn_s_barrier();

        const char* Ab = lds[kc & 3];
        const char* Bb = lds[kc & 3] + 8192;
        {
            const int r = wave * 16 + l15;
            const int g0 = kg * 2;
            f32x4 a0 = *(const f32x4*)(Ab + r * 128 + ((g0 ^ (r & 7)) * 16));
            f32x4 a1 = *(const f32x4*)(Ab + r * 128 + (((g0 + 1) ^ (r & 7)) * 16));
            short8 a;
            a[0] = (short)f2bf(a0[0]); a[1] = (short)f2bf(a0[1]);
            a[2] = (short)f2bf(a0[2]); a[3] = (short)f2bf(a0[3]);
            a[4] = (short)f2bf(a1[0]); a[5] = (short)f2bf(a1[1]);
            a[6] = (short)f2bf(a1[2]); a[7] = (short)f2bf(a1[3]);
#pragma unroll
            for (int nt = 0; nt < 12; ++nt) {
                int rb = nt * 16 + l15;
                short8 bfrag = *(const short8*)(
                    Bb + rb * 64 + ((kg ^ (rb & 3)) * 16));
                acc[nt] = __builtin_amdgcn_mfma_f32_16x16x32_bf16(a, bfrag, acc[nt], 0, 0, 0);
            }
        }
    }
#undef STAGE_CHUNK

    const float cs = 0.04508422f;   // log2(e) / 32  (folded into q)
    const int crow0 = m0 + wave * 16 + (kg << 2);
#pragma unroll
    for (int nt = 0; nt < 12; ++nt) {
        int n = nt * 16 + l15;
        int which = n >> 6;
        int h = n & 63;
#pragma unroll
        for (int r = 0; r < 4; ++r) {
            int gm = crow0 + r;
            float av = acc[nt][r];
            if (which == 1) av *= cs;
            unsigned short v = f2bf(av);
            if (which == 0) {
                kws[(size_t)gm * NH + h] = v;
            } else if (which == 1) {
                qws[(size_t)gm * NH + h] = v;
            } else {
                int bb = gm >> 12, tt = gm & 4095;
                vtws[((size_t)(bb * NH + h)) * NT + tt] = v;
            }
        }
    }
}

// ---------------- Flash attention (causal, swapped operands, split-KV) ---------
// (R6 version, verbatim.) 1024 blocks = 2 KV-halves x (8 batches x 64 q-tiles).
__global__ __launch_bounds__(256) void flash_kernel(
    const unsigned short* __restrict__ qws, const unsigned short* __restrict__ kws,
    const unsigned short* __restrict__ vtws,
    float* __restrict__ opart, float* __restrict__ mlpart)
{
    __shared__ unsigned short Kbuf[2][64 * 64];
    __shared__ unsigned short Vbuf[2][64 * 64];
    __shared__ unsigned short Plds[4 * 16 * 64];   // per-wave 16x64 P strips

    const int id = blockIdx.x;
    const int kvh = id >> 9;           // KV half: 0 = [0,h), 1 = [h,nkv)
    const int rem9 = id & 511;
    const int lighthalf = rem9 >> 8;   // 0: heavy q-tiles, 1: light
    const int rem = rem9 & 255;
    const int b = rem & 7;
    const int i32 = rem >> 3;          // 0..31
    const int qt = lighthalf ? i32 : (63 - i32);
    const int nkv = qt + 1;
    const int hsp = nkv - (nkv >> 1);  // ceil(nkv/2)
    const int k0 = kvh ? hsp : 0;
    const int k1 = kvh ? nkv : hsp;
    const int pid_ = (kvh << 9) | ((b << 6) | qt);

    float* mlp = mlpart + (size_t)pid_ * 128;
    float* op  = opart + (size_t)pid_ * 4096;

    if (k0 >= k1) {                    // empty partition (qt=0, half B)
        f32x4 z = f32x4{0.f, 0.f, 0.f, 0.f};
        f32x4* op4 = (f32x4*)op;
        for (int i = threadIdx.x; i < 1024; i += 256) op4[i] = z;
        if (threadIdx.x < 64) {
            mlp[threadIdx.x] = -INFINITY;
            mlp[64 + threadIdx.x] = 0.f;
        }
        return;
    }

    const int lane = threadIdx.x & 63;
    const int wave = threadIdx.x >> 6;
    const int l15 = lane & 15;
    const int kg = lane >> 4;

    // ---- staging sources (pre-inverse-swizzled, loop-invariant per lane) ----
    const int sg = (lane & 7) ^ (lane >> 3);   // swizzled source granule
    const unsigned short* kSrc[2];
    const unsigned short* vSrc[2];
#pragma unroll
    for (int j = 0; j < 2; ++j) {
        int r = 16 * wave + 8 * j + (lane >> 3);   // tile-local row 0..63
        kSrc[j] = kws + ((size_t)(b * NT) + r) * NH + sg * 8;
        vSrc[j] = vtws + ((size_t)(b * NH + r)) * NT + sg * 8;
    }

    // Q fragments (pre-scaled by log2(e)/32): lane holds Q[q=l15][d=kg*8+j]
    short8 qf[2];
    {
        const unsigned short* qp =
            qws + ((size_t)(b * NT + qt * 64 + wave * 16 + l15)) * NH + kg * 8;
        qf[0] = *(const short8*)(qp);
        qf[1] = *(const short8*)(qp + 32);
    }

    f32x4 o[4];        // O^T: o[dt][r] = O[q=l15][d = dt*16 + kg*4 + r]
#pragma unroll
    for (int dt = 0; dt < 4; ++dt) o[dt] = f32x4{0.f, 0.f, 0.f, 0.f};
    float m_r = -INFINITY;   // row max (uniform across the row's 4 kg-lanes)
    float l_r = 0.f;         // per-lane PARTIAL sum (own 16 keys)

    char* pw = (char*)Plds + wave * 2048;
    const int pswz = (l15 & 7) << 4;

    // prologue: stage tile k0 into buf 0
#pragma unroll
    for (int j = 0; j < 2; ++j) {
        int i = 2 * wave + j;
        GLOAD16(kSrc[j] + (size_t)k0 * 64 * NH, (char*)Kbuf[0] + i * 1024);
        GLOAD16(vSrc[j] + (size_t)k0 * 64,      (char*)Vbuf[0] + i * 1024);
    }
    __syncthreads();

    int cur = 0;
    for (int kv = k0; kv < k1; ++kv) {
        // stage next tile into the other buffer (async, fire-and-forget)
        if (kv + 1 < k1) {
#pragma unroll
            for (int j = 0; j < 2; ++j) {
                int i = 2 * wave + j;
                GLOAD16(kSrc[j] + (size_t)(kv + 1) * 64 * NH,
                        (char*)Kbuf[cur ^ 1] + i * 1024);
                GLOAD16(vSrc[j] + (size_t)(kv + 1) * 64,
                        (char*)Vbuf[cur ^ 1] + i * 1024);
            }
        }

        const char* Kb = (const char*)Kbuf[cur];
        const char* Vb = (const char*)Vbuf[cur];

        // S^T = mfma(K, Q): st[jt][r] = S[q=l15][key = jt*16 + kg*4 + r]
        f32x4 st[4];
#pragma unroll
        for (int jt = 0; jt < 4; ++jt) st[jt] = f32x4{0.f, 0.f, 0.f, 0.f};
#pragma unroll
        for (int ks = 0; ks < 2; ++ks) {
            const int cbb = ks * 64 + kg * 16;
#pragma unroll
            for (int jt = 0; jt < 4; ++jt) {
                int krow = jt * 16 + l15;
                short8 kf = *(const short8*)(Kb + krow * 128 +
                                             (cbb ^ ((krow & 7) << 4)));
                st[jt] = __builtin_amdgcn_mfma_f32_16x16x32_bf16(kf, qf[ks], st[jt], 0, 0, 0);
            }
        }

        // causal mask: only the diagonal tile (uniform branch)
        if (kv == qt) {
#pragma unroll
            for (int jt = 0; jt < 4; ++jt)
#pragma unroll
                for (int r = 0; r < 4; ++r)
                    if (jt * 16 + (kg << 2) + r > wave * 16 + l15)
                        st[jt][r] = -1e30f;
        }

        // lane-local max over own 16 keys (no cross-lane)
        float lmax;
        {
            float t0 = fmaxf(fmaxf(st[0][0], st[0][1]), fmaxf(st[0][2], st[0][3]));
            float t1 = fmaxf(fmaxf(st[1][0], st[1][1]), fmaxf(st[1][2], st[1][3]));
            float t2 = fmaxf(fmaxf(st[2][0], st[2][1]), fmaxf(st[2][2], st[2][3]));
            float t3 = fmaxf(fmaxf(st[3][0], st[3][1]), fmaxf(st[3][2], st[3][3]));
            lmax = fmaxf(fmaxf(t0, t1), fmaxf(t2, t3));
        }

        // defer-max: rescale only when some row grew past m+8 (rare)
        if (!__all(lmax <= m_r + 8.0f)) {
            float pmax = lmax;
            pmax = fmaxf(pmax, __shfl_xor(pmax, 16));
            pmax = fmaxf(pmax, __shfl_xor(pmax, 32));
            float mn = fmaxf(m_r, pmax);
            float alpha = __builtin_amdgcn_exp2f(m_r - mn);
            m_r = mn;
            l_r *= alpha;
#pragma unroll
            for (int dt = 0; dt < 4; ++dt)
#pragma unroll
                for (int r = 0; r < 4; ++r)
                    o[dt][r] *= alpha;
        }

        // P = exp2(S - m), bounded by 2^8; accumulate per-lane partial l
#pragma unroll
        for (int jt = 0; jt < 4; ++jt)
#pragma unroll
            for (int r = 0; r < 4; ++r)
                st[jt][r] = __builtin_amdgcn_exp2f(st[jt][r] - m_r);
        {
            float t0 = (st[0][0] + st[0][1]) + (st[0][2] + st[0][3]);
            float t1 = (st[1][0] + st[1][1]) + (st[1][2] + st[1][3]);
            float t2 = (st[2][0] + st[2][1]) + (st[2][2] + st[2][3]);
            float t3 = (st[3][0] + st[3][1]) + (st[3][2] + st[3][3]);
            l_r += (t0 + t1) + (t2 + t3);
        }

        // pack P to bf16, per-wave LDS strip round-trip -> B-frag layout
#pragma unroll
        for (int jt = 0; jt < 4; ++jt) {
            unsigned w0 = cvt_pk_bf16(st[jt][0], st[jt][1]);
            unsigned w1 = cvt_pk_bf16(st[jt][2], st[jt][3]);
            uint2 t; t.x = w0; t.y = w1;
            *(uint2*)(pw + l15 * 128 + ((jt * 32 + kg * 8) ^ pswz)) = t;
        }
        short8 pf[2];
#pragma unroll
        for (int ks = 0; ks < 2; ++ks)
            pf[ks] = *(const short8*)(pw + l15 * 128 + ((ks * 64 + kg * 16) ^ pswz));

        // O^T += mfma(V^T, P^T)
#pragma unroll
        for (int ks = 0; ks < 2; ++ks) {
            const int cbb = ks * 64 + kg * 16;
#pragma unroll
            for (int dt = 0; dt < 4; ++dt) {
                int vrow = dt * 16 + l15;
                short8 vf = *(const short8*)(Vb + vrow * 128 +
                                             (cbb ^ ((vrow & 7) << 4)));
                o[dt] = __builtin_amdgcn_mfma_f32_16x16x32_bf16(vf, pf[ks], o[dt], 0, 0, 0);
            }
        }

        // single barrier: drains staging vmcnt + this iter's LDS reads,
        // making buf[cur] safe to overwrite and buf[cur^1] ready to read.
        __syncthreads();
        cur ^= 1;
    }

    // epilogue: reduce partial l across the row's 4 kg-lanes; store raw O^T + (m,l)
    float lsum = l_r;
    lsum += __shfl_xor(lsum, 16);
    lsum += __shfl_xor(lsum, 32);
    float* orow = op + (wave * 16 + l15) * 64 + (kg << 2);
#pragma unroll
    for (int dt = 0; dt < 4; ++dt)
        *(f32x4*)(orow + dt * 16) = o[dt];
    if (kg == 0) {               // one lane per q-row
        int q = wave * 16 + l15;
        mlp[q] = m_r;
        mlp[64 + q] = lsum;
    }
}

// ---------------- Combine: merge the two KV halves, normalize -----------------
// 512 blocks = (b, qt). O = (eA*OA + eB*OB) / (eA*lA + eB*lB), e = exp2(m - m*).
__global__ __launch_bounds__(256) void combine_kernel(
    const float* __restrict__ opart, const float* __restrict__ mlpart,
    float* __restrict__ out)
{
    const int cid = blockIdx.x;          // = (b<<6)|qt
    const int b = cid >> 6, qt = cid & 63;
    const float* mlA = mlpart + (size_t)cid * 128;
    const float* mlB = mlpart + (size_t)(512 + cid) * 128;
    const f32x4* oA = (const f32x4*)(opart + (size_t)cid * 4096);
    const f32x4* oB = (const f32x4*)(opart + (size_t)(512 + cid) * 4096);
    f32x4* og = (f32x4*)out;

#pragma unroll
    for (int i = 0; i < 4; ++i) {
        int g = threadIdx.x + i * 256;   // 0..1023 f32x4 groups
        int row = g >> 4;
        float mA = mlA[row], lA = mlA[64 + row];
        float mB = mlB[row], lB = mlB[64 + row];
        float ms = fmaxf(mA, mB);
        float eA = __builtin_amdgcn_exp2f(mA - ms);
        float eB = __builtin_amdgcn_exp2f(mB - ms);
        float dinv = __builtin_amdgcn_rcpf(eA * lA + eB * lB);
        f32x4 a = oA[g], c = oB[g];
        f32x4 r;
        r[0] = (eA * a[0] + eB * c[0]) * dinv;
        r[1] = (eA * a[1] + eB * c[1]) * dinv;
        r[2] = (eA * a[2] + eB * c[2]) * dinv;
        r[3] = (eA * a[3] + eB * c[3]) * dinv;
        og[((size_t)(b * NT) + qt * 64 + row) * 16 + (g & 15)] = r;
    }
}

extern "C" void kernel_launch(void* const* d_in, const int* in_sizes, int n_in,
                              void* d_out, int out_size, void* d_ws, size_t ws_size,
                              hipStream_t stream) {
    const float* x  = (const float*)d_in[0];
    const float* Wk = (const float*)d_in[1];
    const float* Wq = (const float*)d_in[2];
    const float* Wv = (const float*)d_in[3];
    float* out = (float*)d_out;

    unsigned short* ws   = (unsigned short*)d_ws;
    const size_t qkv_elems = (size_t)NB * NT * NH;   // 2M elements each
    unsigned short* qws  = ws;
    unsigned short* kws  = qws + qkv_elems;
    unsigned short* vtws = kws + qkv_elems;
    unsigned short* Wt   = vtws + qkv_elems;          // 192*1024 bf16
    float* opart  = (float*)(Wt + (size_t)192 * NC);  // 1024 tiles x 4096 f32
    float* mlpart = opart + (size_t)1024 * 4096;      // 1024 x 128 f32

    wprep_kernel<<<dim3(192), dim3(256), 0, stream>>>(Wk, Wq, Wv, Wt);
    proj_kernel<<<dim3(512), dim3(256), 0, stream>>>(x, Wt, qws, kws, vtws);
    flash_kernel<<<dim3(1024), dim3(256), 0, stream>>>(qws, kws, vtws, opart, mlpart);
    combine_kernel<<<dim3(512), dim3(256), 0, stream>>>(opart, mlpart, out);
}